// Round 1
// baseline (449.761 us; speedup 1.0000x reference)
//
#include <hip/hip_runtime.h>
#include <hip/hip_bf16.h>

using short8 = __attribute__((ext_vector_type(8))) short;
using f32x4  = __attribute__((ext_vector_type(4))) float;

#define NB   64     // batch rows (M)
#define NTOK 32     // tokens per batch row
#define DD   384
#define NE   8      // experts
#define TK   8      // top-k
#define NC   1000
#define KD   3072   // K*D
#define ND   12288  // N*D

__device__ __forceinline__ float gelu_f(float x) {
  return 0.5f * x * (1.0f + erff(x * 0.70710678118654752440f));
}

// f32 -> bf16 round-to-nearest-even (bit trick)
__device__ __forceinline__ unsigned short f2bf(float f) {
  unsigned u = __float_as_uint(f);
  u += 0x7fffu + ((u >> 16) & 1u);
  return (unsigned short)(u >> 16);
}

// ---------------------------------------------------------------------------
// Routing: logits = x[b] @ emb^T, top-8 per (b,e) (softmax is monotonic -> skip),
// gather sel[e][b][k*D+d] = bf16(x[b][I[b,e,k]][d]); also xb = bf16(x).
// ---------------------------------------------------------------------------
__global__ __launch_bounds__(256) void routing_kernel(
    const float* __restrict__ x, const float* __restrict__ emb,
    unsigned short* __restrict__ sel, unsigned short* __restrict__ xb)
{
  __shared__ float xs[NTOK][DD + 1];   // +1 pad: kill stride-384 bank conflicts
  __shared__ float es[NE][DD + 1];
  __shared__ float lg[NE][NTOK];
  __shared__ int   Is[NE][TK];
  const int b = blockIdx.x, tid = threadIdx.x;

  for (int i = tid; i < NTOK * DD; i += 256) xs[i / DD][i % DD] = x[(size_t)b * ND + i];
  for (int i = tid; i < NE * DD;   i += 256) es[i / DD][i % DD] = emb[i];
  __syncthreads();

  {
    const int e = tid >> 5, n = tid & 31;
    float s = 0.f;
    for (int d = 0; d < DD; ++d) s += xs[n][d] * es[e][d];
    lg[e][n] = s;
  }
  __syncthreads();

  if (tid < NE) {   // stable argmax x8: ties -> lowest index, matches lax.top_k
    const int e = tid;
    for (int k = 0; k < TK; ++k) {
      float best = lg[e][0]; int bi = 0;
      for (int n = 1; n < NTOK; ++n) { float v = lg[e][n]; if (v > best) { best = v; bi = n; } }
      Is[e][k] = bi;
      lg[e][bi] = -INFINITY;
    }
  }
  __syncthreads();

  for (int i = tid; i < NE * KD; i += 256) {
    const int e = i / KD, r = i % KD, k = r / DD, d = r % DD;
    const int n = Is[e][k];
    sel[((size_t)e * NB + b) * KD + r] = f2bf(xs[n][d]);
  }
  for (int i = tid; i < ND; i += 256) xb[(size_t)b * ND + i] = f2bf(xs[i / DD][i % DD]);
}

// ---------------------------------------------------------------------------
// Skinny GEMM: C[64][N] = A(bf16,[64][K]) @ W(f32,[K][N]) (+bias, +gelu).
// Block = 4 waves, each wave owns the full 64x32 tile over K/4 (then LDS reduce).
// W fragments loaded straight from global in MFMA B-layout, cvt f32->bf16 in reg.
// SPLIT>1: blockIdx.z splits K across blocks, raw f32 partials to `outv`.
// OUTBF: 1 -> bf16 output, 0 -> f32. NGUARD: column bounds check (N=1000 case).
// ---------------------------------------------------------------------------
template<int SPLIT, bool GELU, int OUTBF, bool NGUARD>
__global__ __launch_bounds__(256) void gemm_m64(
    const unsigned short* __restrict__ A, const float* __restrict__ W,
    const float* __restrict__ bias, void* __restrict__ outv,
    const int K, const int N, const int nbatch)
{
  const int tid = threadIdx.x;
  const int w = tid >> 6, lane = tid & 63;
  const int ln = lane & 15, g8 = (lane >> 4) * 8;
  const int n0 = blockIdx.x * 32;
  const int bt = blockIdx.y, z = blockIdx.z;

  const int kchunk = K / (SPLIT * 4);       // K per wave
  const int kw0    = (z * 4 + w) * kchunk;
  const int nsteps = kchunk / 32;

  const unsigned short* Ab = A + (size_t)bt * 64 * K;
  const float*          Wb = W + (size_t)bt * K * N;

  const int col0 = n0 + ln;
  bool ok0 = true, ok1 = true;
  if (NGUARD) { ok0 = (col0 < N); ok1 = (col0 + 16 < N); }

  f32x4 acc[4][2];
  #pragma unroll
  for (int mt = 0; mt < 4; ++mt) {
    acc[mt][0] = (f32x4){0.f, 0.f, 0.f, 0.f};
    acc[mt][1] = (f32x4){0.f, 0.f, 0.f, 0.f};
  }

  for (int st = 0; st < nsteps; ++st) {
    const int k0 = kw0 + st * 32;
    // B fragments: lane l -> W[k0 + 8*(l>>4) + j][n0 + s*16 + (l&15)]
    const float* wp = Wb + (size_t)(k0 + g8) * N + col0;
    float bv0[8], bv1[8];
    #pragma unroll
    for (int j = 0; j < 8; ++j) {
      bv0[j] = (!NGUARD || ok0) ? wp[(size_t)j * N]      : 0.f;
      bv1[j] = (!NGUARD || ok1) ? wp[(size_t)j * N + 16] : 0.f;
    }
    // A fragments: lane l -> A[mt*16 + (l&15)][k0 + 8*(l>>4) .. +7] (16B load)
    short8 afr[4];
    #pragma unroll
    for (int mt = 0; mt < 4; ++mt)
      afr[mt] = *reinterpret_cast<const short8*>(Ab + (size_t)(mt * 16 + ln) * K + (k0 + g8));
    union { short8 v; unsigned short u[8]; } pb0, pb1;
    #pragma unroll
    for (int j = 0; j < 8; ++j) { pb0.u[j] = f2bf(bv0[j]); pb1.u[j] = f2bf(bv1[j]); }
    #pragma unroll
    for (int mt = 0; mt < 4; ++mt) {
      acc[mt][0] = __builtin_amdgcn_mfma_f32_16x16x32_bf16(afr[mt], pb0.v, acc[mt][0], 0, 0, 0);
      acc[mt][1] = __builtin_amdgcn_mfma_f32_16x16x32_bf16(afr[mt], pb1.v, acc[mt][1], 0, 0, 0);
    }
  }

  // cross-wave K-partial reduction through LDS
  __shared__ float red[4][64 * 32];
  const int rb = (lane >> 4) * 4;   // C/D: col = lane&15, row = (lane>>4)*4 + reg
  #pragma unroll
  for (int mt = 0; mt < 4; ++mt)
    #pragma unroll
    for (int s = 0; s < 2; ++s)
      #pragma unroll
      for (int r = 0; r < 4; ++r)
        red[w][(mt * 16 + rb + r) * 32 + s * 16 + ln] = acc[mt][s][r];
  __syncthreads();

  const int row = tid >> 2, c0 = (tid & 3) * 8;
  float v[8];
  #pragma unroll
  for (int i = 0; i < 8; ++i) {
    const int o = row * 32 + c0 + i;
    v[i] = red[0][o] + red[1][o] + red[2][o] + red[3][o];
  }

  if (SPLIT == 1) {
    #pragma unroll
    for (int i = 0; i < 8; ++i) {
      float t = v[i] + bias[(size_t)bt * N + n0 + c0 + i];
      if (GELU) t = gelu_f(t);
      v[i] = t;
    }
    if (OUTBF) {
      unsigned short* op = (unsigned short*)outv + ((size_t)bt * 64 + row) * N + n0 + c0;
      union { short8 s; unsigned short u[8]; } o;
      #pragma unroll
      for (int i = 0; i < 8; ++i) o.u[i] = f2bf(v[i]);
      *reinterpret_cast<short8*>(op) = o.s;
    } else {
      float* op = (float*)outv + ((size_t)bt * 64 + row) * N + n0 + c0;
      #pragma unroll
      for (int i = 0; i < 8; ++i) op[i] = v[i];
    }
  } else {
    float* op = (float*)outv + (((size_t)z * nbatch + bt) * 64 + row) * N;
    #pragma unroll
    for (int i = 0; i < 8; ++i) {
      const int n = n0 + c0 + i;
      if (!NGUARD || n < N) op[n] = v[i];
    }
  }
}

// ---------------------------------------------------------------------------
// Split-K reduce epilogue: out = act(sum_z part[z] + bias)
// ---------------------------------------------------------------------------
template<int SPLIT, bool GELU, bool OUTBF>
__global__ __launch_bounds__(256) void reduce_ep(
    const float* __restrict__ part, const float* __restrict__ bias,
    void* __restrict__ outv, const int N)
{
  const int total = 64 * N;
  const int idx = blockIdx.x * 256 + threadIdx.x;
  if (idx >= total) return;
  const int n = idx % N;
  float s = 0.f;
  #pragma unroll
  for (int zz = 0; zz < SPLIT; ++zz) s += part[(size_t)zz * total + idx];
  s += bias[n];
  if (GELU) s = gelu_f(s);
  if (OUTBF) ((unsigned short*)outv)[idx] = f2bf(s);
  else       ((float*)outv)[idx] = s;
}

// ---------------------------------------------------------------------------
// Gate: logits[b][e] = t[b] . sw_w2[:,e] + sw_b2[e]; w = softmax over e.
// ---------------------------------------------------------------------------
__global__ __launch_bounds__(256) void swgate_kernel(
    const float* __restrict__ t, const float* __restrict__ w2,
    const float* __restrict__ b2, float* __restrict__ wout)
{
  __shared__ float red[256][8];
  __shared__ float lg[8];
  const int b = blockIdx.x, tid = threadIdx.x;
  float p0=0,p1=0,p2=0,p3=0,p4=0,p5=0,p6=0,p7=0;
  const float* tb = t + (size_t)b * ND;
  for (int i = tid; i < ND; i += 256) {
    const float tv = tb[i];
    const float4* wp = reinterpret_cast<const float4*>(w2 + (size_t)i * 8);
    const float4 wa = wp[0], wc = wp[1];
    p0 += tv * wa.x; p1 += tv * wa.y; p2 += tv * wa.z; p3 += tv * wa.w;
    p4 += tv * wc.x; p5 += tv * wc.y; p6 += tv * wc.z; p7 += tv * wc.w;
  }
  red[tid][0]=p0; red[tid][1]=p1; red[tid][2]=p2; red[tid][3]=p3;
  red[tid][4]=p4; red[tid][5]=p5; red[tid][6]=p6; red[tid][7]=p7;
  __syncthreads();
  if (tid < 8) {
    float s = 0.f;
    for (int i = 0; i < 256; ++i) s += red[i][tid];
    lg[tid] = s + b2[tid];
  }
  __syncthreads();
  if (tid == 0) {
    float mx = lg[0];
    for (int e = 1; e < 8; ++e) mx = fmaxf(mx, lg[e]);
    float sum = 0.f;
    for (int e = 0; e < 8; ++e) sum += expf(lg[e] - mx);
    for (int e = 0; e < 8; ++e) wout[b * 8 + e] = expf(lg[e] - mx) / sum;
  }
}

// ---------------------------------------------------------------------------
// Mix: ws[b][c] = sum_e er[e][b][c] * w[b][e]  -> bf16
// ---------------------------------------------------------------------------
__global__ __launch_bounds__(256) void mix_kernel(
    const float* __restrict__ er, const float* __restrict__ wv,
    unsigned short* __restrict__ wsb)
{
  const int idx = blockIdx.x * 256 + threadIdx.x;   // 64*3072 total
  const int b = idx / KD, c = idx % KD;
  float s = 0.f;
  #pragma unroll
  for (int e = 0; e < NE; ++e) s += er[((size_t)e * NB + b) * KD + c] * wv[b * NE + e];
  wsb[idx] = f2bf(s);
}

// ---------------------------------------------------------------------------
extern "C" void kernel_launch(void* const* d_in, const int* in_sizes, int n_in,
                              void* d_out, int out_size, void* d_ws, size_t ws_size,
                              hipStream_t stream)
{
  (void)in_sizes; (void)n_in; (void)out_size; (void)ws_size;
  const float* x     = (const float*)d_in[0];
  const float* emb   = (const float*)d_in[1];
  const float* w1    = (const float*)d_in[2];
  const float* b1    = (const float*)d_in[3];
  const float* w2    = (const float*)d_in[4];
  const float* b2    = (const float*)d_in[5];
  const float* sw_w1 = (const float*)d_in[6];
  const float* sw_b1 = (const float*)d_in[7];
  const float* sw_w2 = (const float*)d_in[8];
  const float* sw_b2 = (const float*)d_in[9];
  const float* ch_w1 = (const float*)d_in[10];
  const float* ch_b1 = (const float*)d_in[11];
  const float* ch_w2 = (const float*)d_in[12];
  const float* ch_b2 = (const float*)d_in[13];
  float* out = (float*)d_out;

  char* ws = (char*)d_ws;
  size_t off = 0;
  auto alloc = [&](size_t bytes) -> void* {
    void* p = ws + off;
    off += (bytes + 255) & ~(size_t)255;
    return p;
  };
  unsigned short* sel  = (unsigned short*)alloc((size_t)NE * NB * KD * 2);  // bf16 (E,64,KD)
  unsigned short* xb   = (unsigned short*)alloc((size_t)NB * ND * 2);       // bf16 (64,ND)
  unsigned short* h    = (unsigned short*)alloc((size_t)NE * NB * KD * 2);  // bf16 (E,64,KD)
  float*          er   = (float*)alloc((size_t)NE * NB * KD * 4);           // f32  (E,64,KD)
  float*          tpt  = (float*)alloc((size_t)2 * NB * ND * 4);            // sw1 partials
  float*          t    = (float*)alloc((size_t)NB * ND * 4);                // f32  (64,ND)
  float*          wv   = (float*)alloc((size_t)NB * NE * 4);                // gate weights
  unsigned short* wsb  = (unsigned short*)alloc((size_t)NB * KD * 2);       // bf16 (64,KD)
  float*          g1p  = (float*)alloc((size_t)8 * NB * KD * 4);            // ch1 partials
  unsigned short* g1   = (unsigned short*)alloc((size_t)NB * KD * 2);       // bf16 (64,KD)
  float*          g2p  = (float*)alloc((size_t)8 * NB * NC * 4);            // ch2 partials

  // 1) routing + gathers + bf16 casts
  routing_kernel<<<dim3(64), 256, 0, stream>>>(x, emb, sel, xb);
  // 2) expert GEMM1: h = gelu(sel @ w1 + b1)              [bf16 out]
  gemm_m64<1, true, 1, false><<<dim3(96, 8, 1), 256, 0, stream>>>(sel, w1, b1, (void*)h, KD, KD, NE);
  // 3) expert GEMM2: er = h @ w2 + b2                     [f32 out]
  gemm_m64<1, false, 0, false><<<dim3(96, 8, 1), 256, 0, stream>>>(h, w2, b2, (void*)er, KD, KD, NE);
  // 4) sw GEMM1 (split-K x2): tpt = xb @ sw_w1 (partials)
  gemm_m64<2, false, 0, false><<<dim3(384, 1, 2), 256, 0, stream>>>(xb, sw_w1, nullptr, (void*)tpt, ND, ND, 1);
  // 5) t = gelu(sum_z tpt + sw_b1)                        [f32]
  reduce_ep<2, true, false><<<dim3((64 * ND) / 256), 256, 0, stream>>>(tpt, sw_b1, (void*)t, ND);
  // 6) gate softmax
  swgate_kernel<<<dim3(64), 256, 0, stream>>>(t, sw_w2, sw_b2, wv);
  // 7) ws = sum_e er * w                                  [bf16]
  mix_kernel<<<dim3((NB * KD) / 256), 256, 0, stream>>>(er, wv, wsb);
  // 8) ch GEMM1 (split-K x8): g1p = wsb @ ch_w1 (partials)
  gemm_m64<8, false, 0, false><<<dim3(96, 1, 8), 256, 0, stream>>>(wsb, ch_w1, nullptr, (void*)g1p, KD, KD, 1);
  // 9) g1 = gelu(sum_z g1p + ch_b1)                       [bf16]
  reduce_ep<8, true, true><<<dim3((64 * KD) / 256), 256, 0, stream>>>(g1p, ch_b1, (void*)g1, KD);
  // 10) ch GEMM2 (split-K x8, N=1000 guarded): g2p = g1 @ ch_w2
  gemm_m64<8, false, 0, true><<<dim3(32, 1, 8), 256, 0, stream>>>(g1, ch_w2, nullptr, (void*)g2p, KD, NC, 1);
  // 11) out = sum_z g2p + ch_b2                           [f32 -> d_out]
  reduce_ep<8, false, false><<<dim3((64 * NC + 255) / 256), 256, 0, stream>>>(g2p, ch_b2, (void*)out, NC);
}

// Round 2
// 380.326 us; speedup vs baseline: 1.1826x; 1.1826x over previous
//
#include <hip/hip_runtime.h>
#include <hip/hip_bf16.h>

using short8 = __attribute__((ext_vector_type(8))) short;
using f32x4  = __attribute__((ext_vector_type(4))) float;

typedef const __attribute__((address_space(1))) void* gvp;
typedef __attribute__((address_space(3))) void* lvp;

#define NB   64     // batch rows (M)
#define NTOK 32     // tokens per batch row
#define DD   384
#define NE   8      // experts
#define TK   8      // top-k
#define NC   1000
#define KD   3072   // K*D
#define ND   12288  // N*D

__device__ __forceinline__ float gelu_f(float x) {
  return 0.5f * x * (1.0f + erff(x * 0.70710678118654752440f));
}

// f32 -> bf16 round-to-nearest-even (bit trick)
__device__ __forceinline__ unsigned short f2bf(float f) {
  unsigned u = __float_as_uint(f);
  u += 0x7fffu + ((u >> 16) & 1u);
  return (unsigned short)(u >> 16);
}

// ---------------------------------------------------------------------------
// Routing: logits = x[b] @ emb^T, top-8 per (b,e) (softmax monotonic -> skip),
// gather sel[e][b][k*D+d] = bf16(x[b][I[b,e,k]][d]); also xb = bf16(x).
// ---------------------------------------------------------------------------
__global__ __launch_bounds__(256) void routing_kernel(
    const float* __restrict__ x, const float* __restrict__ emb,
    unsigned short* __restrict__ sel, unsigned short* __restrict__ xb)
{
  __shared__ float xs[NTOK][DD + 1];   // +1 pad: kill stride-384 bank conflicts
  __shared__ float es[NE][DD + 1];
  __shared__ float lg[NE][NTOK];
  __shared__ int   Is[NE][TK];
  const int b = blockIdx.x, tid = threadIdx.x;

  for (int i = tid; i < NTOK * DD; i += 256) xs[i / DD][i % DD] = x[(size_t)b * ND + i];
  for (int i = tid; i < NE * DD;   i += 256) es[i / DD][i % DD] = emb[i];
  __syncthreads();

  {
    const int e = tid >> 5, n = tid & 31;
    float s = 0.f;
    for (int d = 0; d < DD; ++d) s += xs[n][d] * es[e][d];
    lg[e][n] = s;
  }
  __syncthreads();

  if (tid < NE) {   // stable argmax x8: ties -> lowest index, matches lax.top_k
    const int e = tid;
    for (int k = 0; k < TK; ++k) {
      float best = lg[e][0]; int bi = 0;
      for (int n = 1; n < NTOK; ++n) { float v = lg[e][n]; if (v > best) { best = v; bi = n; } }
      Is[e][k] = bi;
      lg[e][bi] = -INFINITY;
    }
  }
  __syncthreads();

  for (int i = tid; i < NE * KD; i += 256) {
    const int e = i / KD, r = i % KD, k = r / DD, d = r % DD;
    const int n = Is[e][k];
    sel[((size_t)e * NB + b) * KD + r] = f2bf(xs[n][d]);
  }
  for (int i = tid; i < ND; i += 256) xb[(size_t)b * ND + i] = f2bf(xs[i / DD][i % DD]);
}

// ---------------------------------------------------------------------------
// Skinny GEMM v2: partial[z] = A(bf16,[64][K])[:, zK/S:(z+1)K/S] @ W(f32 slice)
// Block tile 64x128, 4 waves split n (each 64x32 over full block-K).
// W staged global->LDS (width-16 global_load_lds), double-buffered 2x16KB,
// 512B-contiguous per row-visit (DRAM page efficiency), with an 8-float
// rotation per 8-row group applied on the SOURCE address so linear LDS dest
// receives the swizzled layout; ds_read applies the same rotation (2-way
// bank aliasing = free). Always writes f32 partials [SPLIT][nbatch][64][N];
// bias/activation fused into the reduce epilogue.
// ---------------------------------------------------------------------------
template<int K, int N, int SPLIT, bool NGUARD>
__global__ __launch_bounds__(256) void gemm2(
    const unsigned short* __restrict__ A, const float* __restrict__ W,
    float* __restrict__ outp, const int nbatch)
{
  constexpr int KCH = K / SPLIT;
  constexpr int NSTEP = KCH / 32;
  __shared__ float lw[2][4096];      // [buf][32 rows x 128 cols] f32

  const int t = threadIdx.x;
  const int wv = t >> 6, lane = t & 63;
  const int n0 = blockIdx.x * 128;
  const int bt = blockIdx.y, z = blockIdx.z;

  const unsigned short* Ab = A + (size_t)bt * 64 * K + (size_t)z * KCH;
  const float*          Wb = W + (size_t)bt * (size_t)K * N;

  // ---- staging geometry: wave wv stages rows wv*8..+7 of the 32-row step ----
  // LDS float idx = wv*1024 + r*256 + lane*4  (byte = wave-uniform + lane*16)
  // => row = wv*8 + r*2 + (lane>>5), stored col' = (lane&31)*4
  // source col = (col' - (row>>3)*8) & 127 = ((lane&31)*4 - wv*8) & 127
  const int srow = wv * 8 + (lane >> 5);
  const int scol = (((lane & 31) * 4) - wv * 8) & 127;
  const float* gsrc   = Wb + (size_t)(z * KCH + srow) * N + n0 + scol;
  const float* glimit = Wb + (size_t)K * N - 4;       // OOB clamp (NGUARD)
  float* lbase = &lw[0][0] + wv * 1024 + lane * 4;

  auto stage = [&](int bf, int st) {
    const float* g = gsrc + (size_t)st * 32 * N;
    float* l = lbase + bf * 4096;
    #pragma unroll
    for (int r = 0; r < 4; ++r) {
      const float* gp = g + r * 2 * N;
      if (NGUARD && gp > glimit) gp = glimit;   // wrong values land only in discarded cols
      __builtin_amdgcn_global_load_lds((gvp)gp, (lvp)(l + r * 256), 16, 0, 0);
    }
  };

  // ---- compute-side fragment addressing ----
  const int ln = lane & 15, q = lane >> 4, g8 = q * 8;
  const int colp0 = (wv * 32 +      ln + g8) & 127;   // rotated col, subtile 0
  const int colp1 = (wv * 32 + 16 + ln + g8) & 127;   // rotated col, subtile 1
  const unsigned short* ap = Ab + (size_t)ln * K + g8;

  f32x4 acc[4][2];
  #pragma unroll
  for (int mt = 0; mt < 4; ++mt) {
    acc[mt][0] = (f32x4){0.f, 0.f, 0.f, 0.f};
    acc[mt][1] = (f32x4){0.f, 0.f, 0.f, 0.f};
  }

  stage(0, 0);
  for (int st = 0; st < NSTEP; ++st) {
    const int bf = st & 1;
    __syncthreads();                      // drains stage(bf); prev reads of bf^1 done
    if (st + 1 < NSTEP) stage(bf ^ 1, st + 1);

    const float* lb = &lw[bf][0];
    union { short8 v; unsigned short u[8]; } pb0, pb1;
    #pragma unroll
    for (int j = 0; j < 8; ++j) {
      pb0.u[j] = f2bf(lb[(g8 + j) * 128 + colp0]);
      pb1.u[j] = f2bf(lb[(g8 + j) * 128 + colp1]);
    }
    #pragma unroll
    for (int mt = 0; mt < 4; ++mt) {
      const short8 afr = *reinterpret_cast<const short8*>(ap + (size_t)mt * 16 * K + st * 32);
      acc[mt][0] = __builtin_amdgcn_mfma_f32_16x16x32_bf16(afr, pb0.v, acc[mt][0], 0, 0, 0);
      acc[mt][1] = __builtin_amdgcn_mfma_f32_16x16x32_bf16(afr, pb1.v, acc[mt][1], 0, 0, 0);
    }
  }

  // ---- epilogue: direct f32 partial store (C/D: col=ln, row=q*4+reg) ----
  float* op = outp + (size_t)(z * nbatch + bt) * 64 * N;
  #pragma unroll
  for (int mt = 0; mt < 4; ++mt)
    #pragma unroll
    for (int s = 0; s < 2; ++s) {
      const int col = n0 + wv * 32 + s * 16 + ln;
      if (NGUARD && col >= N) continue;
      #pragma unroll
      for (int r = 0; r < 4; ++r) {
        const int m = mt * 16 + q * 4 + r;
        op[(size_t)m * N + col] = acc[mt][s][r];
      }
    }
}

// ---------------------------------------------------------------------------
// Split-K reduce epilogue: out = act(sum_z part[z] + bias[bt][n])
// part layout [SPLIT][nbatch][64][N]
// ---------------------------------------------------------------------------
template<int SPLIT, bool GELU, bool OUTBF>
__global__ __launch_bounds__(256) void reduce_ep(
    const float* __restrict__ part, const float* __restrict__ bias,
    void* __restrict__ outv, const int N, const int nbatch)
{
  const int total = nbatch * 64 * N;
  const int idx = blockIdx.x * 256 + threadIdx.x;
  if (idx >= total) return;
  const int n = idx % N;
  const int bt = idx / (64 * N);
  float s = 0.f;
  #pragma unroll
  for (int zz = 0; zz < SPLIT; ++zz) s += part[(size_t)zz * total + idx];
  s += bias[(size_t)bt * N + n];
  if (GELU) s = gelu_f(s);
  if (OUTBF) ((unsigned short*)outv)[idx] = f2bf(s);
  else       ((float*)outv)[idx] = s;
}

// ---------------------------------------------------------------------------
// Gate: logits[b][e] = t[b] . sw_w2[:,e] + sw_b2[e]; w = softmax over e.
// ---------------------------------------------------------------------------
__global__ __launch_bounds__(256) void swgate_kernel(
    const float* __restrict__ t, const float* __restrict__ w2,
    const float* __restrict__ b2, float* __restrict__ wout)
{
  __shared__ float red[256][8];
  __shared__ float lg[8];
  const int b = blockIdx.x, tid = threadIdx.x;
  float p0=0,p1=0,p2=0,p3=0,p4=0,p5=0,p6=0,p7=0;
  const float* tb = t + (size_t)b * ND;
  for (int i = tid; i < ND; i += 256) {
    const float tv = tb[i];
    const float4* wp = reinterpret_cast<const float4*>(w2 + (size_t)i * 8);
    const float4 wa = wp[0], wc = wp[1];
    p0 += tv * wa.x; p1 += tv * wa.y; p2 += tv * wa.z; p3 += tv * wa.w;
    p4 += tv * wc.x; p5 += tv * wc.y; p6 += tv * wc.z; p7 += tv * wc.w;
  }
  red[tid][0]=p0; red[tid][1]=p1; red[tid][2]=p2; red[tid][3]=p3;
  red[tid][4]=p4; red[tid][5]=p5; red[tid][6]=p6; red[tid][7]=p7;
  __syncthreads();
  if (tid < 8) {
    float s = 0.f;
    for (int i = 0; i < 256; ++i) s += red[i][tid];
    lg[tid] = s + b2[tid];
  }
  __syncthreads();
  if (tid == 0) {
    float mx = lg[0];
    for (int e = 1; e < 8; ++e) mx = fmaxf(mx, lg[e]);
    float sum = 0.f;
    for (int e = 0; e < 8; ++e) sum += expf(lg[e] - mx);
    for (int e = 0; e < 8; ++e) wout[b * 8 + e] = expf(lg[e] - mx) / sum;
  }
}

// ---------------------------------------------------------------------------
// Fused expert-GEMM2 reduce + mix:
// ws[b][c] = sum_e wv[b][e] * (sum_z part[((z*8+e)*64+b)*KD + c] + b2[e][c])
// ---------------------------------------------------------------------------
__global__ __launch_bounds__(256) void mix2_kernel(
    const float* __restrict__ part, const float* __restrict__ b2,
    const float* __restrict__ wv, unsigned short* __restrict__ wsb)
{
  const int idx = blockIdx.x * 256 + threadIdx.x;   // 64*KD total
  const int b = idx / KD, c = idx % KD;
  float s = 0.f;
  #pragma unroll
  for (int e = 0; e < NE; ++e) {
    float v = b2[(size_t)e * KD + c];
    #pragma unroll
    for (int zz = 0; zz < 4; ++zz)
      v += part[((size_t)(zz * NE + e) * NB + b) * KD + c];
    s += v * wv[b * NE + e];
  }
  wsb[idx] = f2bf(s);
}

// ---------------------------------------------------------------------------
extern "C" void kernel_launch(void* const* d_in, const int* in_sizes, int n_in,
                              void* d_out, int out_size, void* d_ws, size_t ws_size,
                              hipStream_t stream)
{
  (void)in_sizes; (void)n_in; (void)out_size; (void)ws_size;
  const float* x     = (const float*)d_in[0];
  const float* emb   = (const float*)d_in[1];
  const float* w1    = (const float*)d_in[2];
  const float* b1    = (const float*)d_in[3];
  const float* w2    = (const float*)d_in[4];
  const float* b2    = (const float*)d_in[5];
  const float* sw_w1 = (const float*)d_in[6];
  const float* sw_b1 = (const float*)d_in[7];
  const float* sw_w2 = (const float*)d_in[8];
  const float* sw_b2 = (const float*)d_in[9];
  const float* ch_w1 = (const float*)d_in[10];
  const float* ch_b1 = (const float*)d_in[11];
  const float* ch_w2 = (const float*)d_in[12];
  const float* ch_b2 = (const float*)d_in[13];
  float* out = (float*)d_out;

  char* ws = (char*)d_ws;
  size_t off = 0;
  auto alloc = [&](size_t bytes) -> void* {
    void* p = ws + off;
    off += (bytes + 255) & ~(size_t)255;
    return p;
  };
  unsigned short* sel  = (unsigned short*)alloc((size_t)NE * NB * KD * 2);  // bf16 (E,64,KD)
  unsigned short* xb   = (unsigned short*)alloc((size_t)NB * ND * 2);       // bf16 (64,ND)
  unsigned short* h    = (unsigned short*)alloc((size_t)NE * NB * KD * 2);  // bf16 (E,64,KD)
  float*          ep   = (float*)alloc((size_t)4 * NE * NB * KD * 4);       // expert partials (z4)
  float*          tpt  = (float*)alloc((size_t)8 * NB * ND * 4);            // sw1 partials (z8)
  float*          tt   = (float*)alloc((size_t)NB * ND * 4);                // f32 (64,ND)
  float*          wv   = (float*)alloc((size_t)NB * NE * 4);                // gate weights
  unsigned short* wsb  = (unsigned short*)alloc((size_t)NB * KD * 2);       // bf16 (64,KD)
  float*          g1p  = (float*)alloc((size_t)16 * NB * KD * 4);           // ch1 partials (z16)
  unsigned short* g1   = (unsigned short*)alloc((size_t)NB * KD * 2);       // bf16 (64,KD)
  float*          g2p  = (float*)alloc((size_t)32 * NB * NC * 4);           // ch2 partials (z32)

  // 1) routing + gathers + bf16 casts
  routing_kernel<<<dim3(64), 256, 0, stream>>>(x, emb, sel, xb);
  // 2) expert GEMM1 partials: ep = sel @ w1 (z4)
  gemm2<KD, KD, 4, false><<<dim3(24, 8, 4), 256, 0, stream>>>(sel, w1, ep, 8);
  // 3) h = gelu(sum_z ep + b1)  [bf16]
  reduce_ep<4, true, true><<<dim3(6144), 256, 0, stream>>>(ep, b1, (void*)h, KD, 8);
  // 4) expert GEMM2 partials: ep = h @ w2 (z4)  [reuse buffer]
  gemm2<KD, KD, 4, false><<<dim3(24, 8, 4), 256, 0, stream>>>(h, w2, ep, 8);
  // 5) sw GEMM1 partials: tpt = xb @ sw_w1 (z8)
  gemm2<ND, ND, 8, false><<<dim3(96, 1, 8), 256, 0, stream>>>(xb, sw_w1, tpt, 1);
  // 6) t = gelu(sum_z tpt + sw_b1)  [f32]
  reduce_ep<8, true, false><<<dim3(3072), 256, 0, stream>>>(tpt, sw_b1, (void*)tt, ND, 1);
  // 7) gate softmax
  swgate_kernel<<<dim3(64), 256, 0, stream>>>(tt, sw_w2, sw_b2, wv);
  // 8) ws = sum_e (sum_z ep + b2) * w  [bf16, fused reduce+mix]
  mix2_kernel<<<dim3((NB * KD) / 256), 256, 0, stream>>>(ep, b2, wv, wsb);
  // 9) ch GEMM1 partials: g1p = wsb @ ch_w1 (z16)
  gemm2<KD, KD, 16, false><<<dim3(24, 1, 16), 256, 0, stream>>>(wsb, ch_w1, g1p, 1);
  // 10) g1 = gelu(sum_z g1p + ch_b1)  [bf16]
  reduce_ep<16, true, true><<<dim3(768), 256, 0, stream>>>(g1p, ch_b1, (void*)g1, KD, 1);
  // 11) ch GEMM2 partials (N=1000, guarded): g2p = g1 @ ch_w2 (z32)
  gemm2<KD, NC, 32, true><<<dim3(8, 1, 32), 256, 0, stream>>>(g1, ch_w2, g2p, 1);
  // 12) out = sum_z g2p + ch_b2  [f32 -> d_out]
  reduce_ep<32, false, false><<<dim3((NB * NC + 255) / 256), 256, 0, stream>>>(g2p, ch_b2, (void*)out, NC, 1);
}